// Round 6
// baseline (583.271 us; speedup 1.0000x reference)
//
#include <hip/hip_runtime.h>
#include <hip/hip_bf16.h>

#define Hh 256
#define Ii 128
#define KF 384    // 128 (x) + 256 (hx) feature dim
#define KB 64     // k-rows per block tile

typedef __attribute__((ext_vector_type(8))) short bf16x8;
typedef __attribute__((ext_vector_type(4))) float f32x4;
typedef unsigned short u16;
typedef unsigned int u32;

__device__ inline float bf2f(u16 u) { return __uint_as_float(((u32)u) << 16); }
__device__ inline u16 f2bf(float f) {
  u32 u = __float_as_uint(f);
  u += 0x7FFFu + ((u >> 16) & 1u);   // RNE
  return (u16)(u >> 16);
}
__device__ inline u32 pack_bf16x2(float a, float b) {
  __hip_bfloat162 h = __float22bfloat162_rn(make_float2(a, b));
  u32 r; __builtin_memcpy(&r, &h, 4); return r;
}
// scale packed bf16 pair by (va, vb), repack
__device__ inline u32 scale2(u32 packed, float va, float vb) {
  float lo = __uint_as_float(packed << 16) * va;
  float hi = __uint_as_float(packed & 0xFFFF0000u) * vb;
  return pack_bf16x2(lo, hi);
}
__device__ inline float sigm(float x) { return 1.0f / (1.0f + __expf(-x)); }
__device__ inline float tanh_f(float x) { return 1.0f - 2.0f / (1.0f + __expf(2.0f * x)); }

// async global->LDS, 16B per lane; lds dest = wave-uniform base + lane*16
__device__ __forceinline__ void gld_lds16(const u16* g, u16* l) {
  __builtin_amdgcn_global_load_lds(
      (const __attribute__((address_space(1))) u32*)g,
      (__attribute__((address_space(3))) u32*)l, 16, 0, 0);
}

union U32x4 { bf16x8 f; u32 d[4]; uint4 v; };

// ---------------- kernel 0: pack weights/bias/Uinv, transpose Vtinv ----------
__global__ __launch_bounds__(256) void k_prep(
    const float* __restrict__ Wii, const float* __restrict__ Wif, const float* __restrict__ Wig,
    const float* __restrict__ Whi, const float* __restrict__ Whit,
    const float* __restrict__ Whf, const float* __restrict__ Whft,
    const float* __restrict__ Whc, const float* __restrict__ Whct,
    const float* __restrict__ Vtinv, const float* __restrict__ Uinv,
    const float* __restrict__ bi, const float* __restrict__ bfm, const float* __restrict__ bg,
    u16* __restrict__ RW, u16* __restrict__ CW, u16* __restrict__ Vtt,
    u16* __restrict__ biasP, float* __restrict__ UinvP, float* __restrict__ proj) {
  const int tid = threadIdx.x, bx = blockIdx.x, y = blockIdx.y;
  if (y < 3) {
    const float* WX  = (y == 0) ? Wii : (y == 1 ? Wif : Wig);
    const float* WHr = (y == 0) ? Whi : (y == 1 ? Whf : Whc);
    const float* WHt = (y == 0) ? Whit : (y == 1 ? Whft : Whct);
    u16* rw = RW + y * Hh * KF;
    u16* cw = CW + y * Hh * KF;
#pragma unroll
    for (int it = 0; it < 4; ++it) {
      int idx = it * 24576 + bx * 256 + tid;   // 0..98303
      int h = idx / KF, t = idx - h * KF;
      float a, c;
      if (t < Ii) { a = WX[h * Ii + t]; c = a; }
      else        { a = WHr[h * Hh + t - Ii]; c = WHt[h * Hh + t - Ii]; }
      rw[idx] = f2bf(a);
      cw[idx] = f2bf(c);
    }
  } else if (y == 3) {
    if (bx < 64) {
      // Vtt[i][k] = Vtinv[k][i], 32x32 LDS tile transpose
      __shared__ u16 tbuf[32][33];
      const int c = tid & 31, r8 = tid >> 5;
      const int tr = bx >> 3, tc = bx & 7;
#pragma unroll
      for (int rr = r8; rr < 32; rr += 8)
        tbuf[rr][c] = f2bf(Vtinv[(tc * 32 + rr) * Hh + tr * 32 + c]);
      __syncthreads();
#pragma unroll
      for (int rr = r8; rr < 32; rr += 8)
        Vtt[(tr * 32 + rr) * Hh + tc * 32 + c] = tbuf[c][rr];
    } else if (bx < 96) {
      const int base = (bx - 64) * 256 + tid;
      const float4 z = {0.f, 0.f, 0.f, 0.f};
#pragma unroll
      for (int it = 0; it < 4; ++it)
        *(float4*)(proj + (size_t)(it * 8192 + base) * 4) = z;
    }
  } else if (y == 4) {
    // biasP: f = ((ph*4+jb)*4+kb)*4096 + t*16 + e ; e = tk*4+r
    const int base = (bx * 256 + tid) * 8;
#pragma unroll
    for (int e8 = 0; e8 < 8; ++e8) {
      int f = base + e8;                    // 0..196607
      int ph = f >> 16;
      int r1 = f & 65535;
      int jb = r1 >> 14;
      int r2 = r1 & 16383;
      int kb = r2 >> 12;
      int r3 = r2 & 4095;
      int t  = r3 >> 4;
      int e  = r3 & 15;
      int w = t >> 6, quad = (t >> 4) & 3, r15 = t & 15;
      int tk = e >> 2, rr = e & 3;
      int j   = jb * 64 + w * 16 + quad * 4 + rr;
      int col = kb * 64 + tk * 16 + r15;
      const float* src = (ph == 0) ? bg : (ph == 1 ? bi : bfm);
      biasP[f] = f2bf(src[j * Hh + col]);
    }
  } else {
    // UinvP: f = (jb*256 + t)*64 + ti*16 + tj*4 + r
    if (bx < 32) {
      const int base = (bx * 256 + tid) * 8;
#pragma unroll
      for (int e8 = 0; e8 < 8; ++e8) {
        int f = base + e8;                  // 0..65535
        int jb = f >> 14;
        int r2 = f & 16383;
        int t  = r2 >> 6;
        int e  = r2 & 63;
        int ti = e >> 4, tj = (e >> 2) & 3, rr = e & 3;
        int w = t >> 6, quad = (t >> 4) & 3, r15 = t & 15;
        int i = w * 64 + ti * 16 + quad * 4 + rr;
        int j = jb * 64 + tj * 16 + r15;
        UinvP[f] = Uinv[i * Hh + j];
      }
    }
  }
}

// ---------------- kernel 1: fused gates + cell + down-projection -------------
// grid 8192 = b(512) x jb(4) x kb(4); 256 threads = 4 waves.
// B (raw CW) staged via global_load_lds into XOR-slotted dbuf (DMA, no VALU);
// A (RW rows) scaled by v in registers; p/c in registers; c-tile -> aliased
// LDS buf0 once; projection MFMA + UinvP weighting; atomic proj add.
__global__ __launch_bounds__(256) void k_main(
    const float* __restrict__ x, const float* __restrict__ hx, const float* __restrict__ cx,
    const u16* __restrict__ RW, const u16* __restrict__ CW,
    const u16* __restrict__ Vtt, const u16* __restrict__ biasP,
    const float* __restrict__ UinvP, float* __restrict__ proj) {
  __shared__ u16 sB[2 * 4096];   // 16 KB; [buf][row(64)][slot(8)][e(8)]; buf0 = sP later
  __shared__ float sV[KF];       //  1.5 KB

  const int tid  = threadIdx.x;
  const int b    = blockIdx.x >> 4;
  const int jb   = (blockIdx.x >> 2) & 3;
  const int kb   = blockIdx.x & 3;
  const int k0   = kb * KB;
  const int lane = tid & 63;
  const int w    = tid >> 6;
  const int r15  = lane & 15;
  const int quad = lane >> 4;
  const int jbase = jb * 64 + w * 16;     // wave's 16 gate rows (global j)

  if (tid < Ii) sV[tid] = x[b * Ii + tid];
  sV[Ii + tid] = hx[b * Hh + tid];

  // phase order: g (tanh), i, f  -> gate indices 2, 0, 1
  const u16* rwp[3] = {RW + 2 * Hh * KF, RW, RW + 1 * Hh * KF};
  const u16* cwp[3] = {CW + 2 * Hh * KF, CW, CW + 1 * Hh * KF};
  const float* cx_b = cx + (size_t)b * Hh * Hh;

  // staging geometry: wave w covers flat slots [w*128, w*128+128)
  const int flat0 = w * 128 + lane;          // issue 0
  const int row0  = flat0 >> 3, sl0 = flat0 & 7;
  const int flat1 = flat0 + 64;              // issue 1
  const int row1  = flat1 >> 3, sl1 = flat1 & 7;
  const size_t goff0 = (size_t)(k0 + row0) * KF + (sl0 ^ (row0 & 7)) * 8;
  const size_t goff1 = (size_t)(k0 + row1) * KF + (sl1 ^ (row1 & 7)) * 8;

  // stage chunk 0 (phase 0, t0 = 0) into buf 0
  gld_lds16(cwp[0] + goff0, sB + w * 1024);
  gld_lds16(cwp[0] + goff1, sB + w * 1024 + 512);
  // prefetch A frags for chunk 0 (raw)
  bf16x8 fan[2];
  fan[0] = *(const bf16x8*)(rwp[0] + (size_t)(jbase + r15) * KF + quad * 8);
  fan[1] = *(const bf16x8*)(rwp[0] + (size_t)(jbase + r15) * KF + 32 + quad * 8);
  __syncthreads();   // sV + chunk0 DMA complete

  float p[4][4];
  f32x4 acc[4];

#pragma unroll
  for (int ph = 0; ph < 3; ++ph) {
#pragma unroll
    for (int tk = 0; tk < 4; ++tk)
#pragma unroll
      for (int r = 0; r < 4; ++r) acc[tk][r] = 0.0f;

#pragma unroll
    for (int kc = 0; kc < 6; ++kc) {
      const int sc  = ph * 6 + kc;
      const int cur = sc & 1;
      const int tb  = kc * 64;                       // current chunk t-base
      const int nph = (kc < 5) ? ph : ph + 1;        // next chunk gate phase
      const int nt0 = (kc < 5) ? (kc + 1) * 64 : 0;  // next chunk t-base

      // stage next chunk via DMA (crosses the barrier; lands by next iter)
      if (sc < 17) {
        gld_lds16(cwp[nph] + goff0 + nt0, sB + (cur ^ 1) * 4096 + w * 1024);
        gld_lds16(cwp[nph] + goff1 + nt0, sB + (cur ^ 1) * 4096 + w * 1024 + 512);
      }

      // scale current A frags by v (register-side diag fold)
      bf16x8 fa[2];
#pragma unroll
      for (int ks = 0; ks < 2; ++ks) {
        const float4 v0 = *(const float4*)(&sV[tb + ks * 32 + quad * 8]);
        const float4 v1 = *(const float4*)(&sV[tb + ks * 32 + quad * 8 + 4]);
        U32x4 a, o;
        a.f = fan[ks];
        o.d[0] = scale2(a.d[0], v0.x, v0.y);
        o.d[1] = scale2(a.d[1], v0.z, v0.w);
        o.d[2] = scale2(a.d[2], v1.x, v1.y);
        o.d[3] = scale2(a.d[3], v1.z, v1.w);
        fa[ks] = o.f;
      }
      // prefetch next A frags (raw)
      if (sc < 17) {
        fan[0] = *(const bf16x8*)(rwp[nph] + (size_t)(jbase + r15) * KF + nt0 + quad * 8);
        fan[1] = *(const bf16x8*)(rwp[nph] + (size_t)(jbase + r15) * KF + nt0 + 32 + quad * 8);
      }

      // MFMA over the staged chunk (XOR-slot read: 2-way conflicts only)
#pragma unroll
      for (int ks = 0; ks < 2; ++ks) {
#pragma unroll
        for (int tk = 0; tk < 4; ++tk) {
          const int row = tk * 16 + r15;
          const int sl  = ((ks * 4 + quad) ^ (r15 & 7)) * 8;
          const bf16x8 fb = *(const bf16x8*)(&sB[cur * 4096 + row * 64 + sl]);
          acc[tk] = __builtin_amdgcn_mfma_f32_16x16x32_bf16(fa[ks], fb, acc[tk], 0, 0, 0);
        }
      }

      if (kc == 5) {
        // combine. C layout: col(k)=tk*16+r15, row(j)=jbase+quad*4+r
        const u16* bp = biasP + ((size_t)((ph * 4 + jb) * 4 + kb) * 256 + tid) * 16;
        const uint4 b0 = *(const uint4*)bp;
        const uint4 b1 = *(const uint4*)(bp + 8);
        const u32 bw[8] = {b0.x, b0.y, b0.z, b0.w, b1.x, b1.y, b1.z, b1.w};
        if (ph == 2) {
          float cxv[16];
#pragma unroll
          for (int tk = 0; tk < 4; ++tk)
#pragma unroll
            for (int r = 0; r < 4; ++r)
              cxv[tk * 4 + r] = cx_b[(size_t)(jbase + quad * 4 + r) * Hh + k0 + tk * 16 + r15];
          // c -> sP (aliased buf0; buf0 is dead after sc=16's barrier)
#pragma unroll
          for (int tk = 0; tk < 4; ++tk)
#pragma unroll
            for (int r = 0; r < 4; ++r) {
              const int e = tk * 4 + r;
              const float bias = (e & 1) ? __uint_as_float(bw[e >> 1] & 0xFFFF0000u)
                                         : __uint_as_float(bw[e >> 1] << 16);
              const float z = acc[tk][r] + bias;
              const float c = sigm(z) * cxv[e] + p[tk][r];
              const int jr = w * 16 + quad * 4 + r;       // local j in [0,64)
              const int kk = tk * 16 + r15;
              const int sl = ((kk >> 3) ^ (jr & 7)) * 8 + (kk & 7);
              sB[jr * 64 + sl] = f2bf(c);
            }
        } else {
#pragma unroll
          for (int tk = 0; tk < 4; ++tk)
#pragma unroll
            for (int r = 0; r < 4; ++r) {
              const int e = tk * 4 + r;
              const float bias = (e & 1) ? __uint_as_float(bw[e >> 1] & 0xFFFF0000u)
                                         : __uint_as_float(bw[e >> 1] << 16);
              const float z = acc[tk][r] + bias;
              if (ph == 0) p[tk][r] = tanh_f(z);
              else         p[tk][r] *= sigm(z);
            }
        }
      }
      __syncthreads();
    }
  }

  // ---- projection: M[i,j] = sum_k Vt_t[i,k] c[j,k]; racc[i] += M*UinvP ----
  bf16x8 fbp[2][4];
#pragma unroll
  for (int ks = 0; ks < 2; ++ks)
#pragma unroll
    for (int tj = 0; tj < 4; ++tj) {
      const int j = tj * 16 + r15;
      const int sl = ((ks * 4 + quad) ^ (j & 7)) * 8;
      fbp[ks][tj] = *(const bf16x8*)(&sB[j * 64 + sl]);
    }

  float racc[4][4];
#pragma unroll
  for (int ti = 0; ti < 4; ++ti)
#pragma unroll
    for (int r = 0; r < 4; ++r) racc[ti][r] = 0.0f;

  const float* up = UinvP + ((size_t)jb * 256 + tid) * 64;
#pragma unroll
  for (int ti = 0; ti < 4; ++ti) {
    const bf16x8 va0 = *(const bf16x8*)(Vtt + (size_t)(w * 64 + ti * 16 + r15) * Hh + k0 + quad * 8);
    const bf16x8 va1 = *(const bf16x8*)(Vtt + (size_t)(w * 64 + ti * 16 + r15) * Hh + k0 + 32 + quad * 8);
    f32x4 pacc[4];
#pragma unroll
    for (int tj = 0; tj < 4; ++tj)
#pragma unroll
      for (int r = 0; r < 4; ++r) pacc[tj][r] = 0.0f;
#pragma unroll
    for (int tj = 0; tj < 4; ++tj)
      pacc[tj] = __builtin_amdgcn_mfma_f32_16x16x32_bf16(va0, fbp[0][tj], pacc[tj], 0, 0, 0);
#pragma unroll
    for (int tj = 0; tj < 4; ++tj)
      pacc[tj] = __builtin_amdgcn_mfma_f32_16x16x32_bf16(va1, fbp[1][tj], pacc[tj], 0, 0, 0);
#pragma unroll
    for (int tj = 0; tj < 4; ++tj) {
      const float4 u = *(const float4*)(up + ti * 16 + tj * 4);
      racc[ti][0] += pacc[tj][0] * u.x;
      racc[ti][1] += pacc[tj][1] * u.y;
      racc[ti][2] += pacc[tj][2] * u.z;
      racc[ti][3] += pacc[tj][3] * u.w;
    }
  }

#pragma unroll
  for (int ti = 0; ti < 4; ++ti)
#pragma unroll
    for (int r = 0; r < 4; ++r) {
      float v = racc[ti][r];
      v += __shfl_xor(v, 1);
      v += __shfl_xor(v, 2);
      v += __shfl_xor(v, 4);
      v += __shfl_xor(v, 8);
      if (r15 == 0) atomicAdd(&proj[b * Hh + w * 64 + ti * 16 + quad * 4 + r], v);
    }
}

// ---------------- kernel 2: o-gate + final output ---------------------------
__global__ __launch_bounds__(256) void k_out(
    const float* __restrict__ x, const float* __restrict__ hx,
    const float* __restrict__ Wio, const float* __restrict__ Who,
    const float* __restrict__ bo, const float* __restrict__ proj,
    float* __restrict__ out) {
  __shared__ float sv[KF];
  const int b = blockIdx.x, tid = threadIdx.x;
  const int lane = tid & 63, w = tid >> 6;
  if (tid < Ii) sv[tid] = x[b * Ii + tid];
  sv[Ii + tid] = hx[b * Hh + tid];
  __syncthreads();
  for (int rr = 0; rr < 64; ++rr) {
    const int h = w * 64 + rr;
    float p = Wio[h * Ii + lane]        * sv[lane]
            + Wio[h * Ii + 64 + lane]   * sv[64 + lane]
            + Who[h * Hh + lane]        * sv[128 + lane]
            + Who[h * Hh + 64 + lane]   * sv[192 + lane]
            + Who[h * Hh + 128 + lane]  * sv[256 + lane]
            + Who[h * Hh + 192 + lane]  * sv[320 + lane];
    p += __shfl_xor(p, 32);
    p += __shfl_xor(p, 16);
    p += __shfl_xor(p, 8);
    p += __shfl_xor(p, 4);
    p += __shfl_xor(p, 2);
    p += __shfl_xor(p, 1);
    if (lane == 0)
      out[b * Hh + h] = sigm(p + bo[h]) * sigm(proj[b * Hh + h]);
  }
}

extern "C" void kernel_launch(void* const* d_in, const int* in_sizes, int n_in,
                              void* d_out, int out_size, void* d_ws, size_t ws_size,
                              hipStream_t stream) {
  (void)in_sizes; (void)n_in; (void)out_size; (void)ws_size;
  const float* x    = (const float*)d_in[0];
  const float* hx   = (const float*)d_in[1];
  const float* cx   = (const float*)d_in[2];
  const float* Wii  = (const float*)d_in[3];
  const float* Wif  = (const float*)d_in[4];
  const float* Wig  = (const float*)d_in[5];
  const float* Wio  = (const float*)d_in[6];
  const float* Whi  = (const float*)d_in[7];
  const float* Whit = (const float*)d_in[8];
  const float* Whf  = (const float*)d_in[9];
  const float* Whft = (const float*)d_in[10];
  const float* Whc  = (const float*)d_in[11];
  const float* Whct = (const float*)d_in[12];
  const float* Who  = (const float*)d_in[13];
  const float* Uinv = (const float*)d_in[14];
  const float* Vtinv= (const float*)d_in[15];
  const float* bi   = (const float*)d_in[16];
  const float* bf   = (const float*)d_in[17];
  const float* bg   = (const float*)d_in[18];
  const float* bo   = (const float*)d_in[19];
  float* out = (float*)d_out;

  // workspace (~2.5 MB): RW[3], CW[3], Vtt, biasP (bf16); UinvP, proj (f32)
  u16* RW    = (u16*)d_ws;
  u16* CW    = RW + 3 * Hh * KF;
  u16* Vtt   = CW + 3 * Hh * KF;
  u16* biasP = Vtt + Hh * Hh;
  float* UinvP = (float*)(biasP + 3 * Hh * Hh);
  float* proj  = UinvP + Hh * Hh;

  k_prep<<<dim3(96, 6), 256, 0, stream>>>(Wii, Wif, Wig, Whi, Whit, Whf, Whft, Whc, Whct,
                                          Vtinv, Uinv, bi, bf, bg,
                                          RW, CW, Vtt, biasP, UinvP, proj);
  k_main<<<8192, 256, 0, stream>>>(x, hx, cx, RW, CW, Vtt, biasP, UinvP, proj);
  k_out<<<512, 256, 0, stream>>>(x, hx, Wio, Who, bo, proj, out);
}